// Round 3
// baseline (114362.341 us; speedup 1.0000x reference)
//
#include <hip/hip_runtime.h>
#include <float.h>

#define N_PTS   50000
#define M_CENT  2048
#define K_LOC   32
#define C_CH    128

typedef unsigned long long u64;
typedef unsigned int u32;

// ---------------- FPS ----------------
// R4-proven protocol (14 worker blocks x 512, leader-wave-only polling, DPP
// reductions). The 14 workers are ELECTED onto a single XCD (runtime checked
// via HW_REG_XCC_ID + a handshake that exercises the actual fast primitive).
//
// R2 measurement: global ATOMICS (with or without sc1) execute at the
// memory-side atomic units -- WRITE_SIZE exploded to 18.3 MB (one HBM-side
// write per atomic) and latency stayed at fabric level (~4280 cyc/iter).
// The only XCD-L2-served primitive is a PLAIN access:
//   store sc0: lands dirty in the local (shared) XCD L2   (~150 cyc to vis)
//   load  sc0: forces L1 miss, served by the XCD L2       (~200-250 cyc)
// Fast mode uses exactly these. Correctness ladder (no HW behavior can hang):
//   (a) the election handshake exercises sc0 store -> sc0 load from 14
//       different CUs, bounded at 512 trips; any timeout => ALL workers
//       unanimously fall back (over the always-coherent sc1 channel) to the
//       original agent-scope protocol (R0, proven 4078 us).
//   (b) main-loop poll: sc0 probes; after 512 fruitless trips every 4th
//       probe is an sc1 agent load (force-miss L1/L2; a force-miss that
//       lands on the locally-dirty L2 line returns the fresh data), so an
//       sc0-load staleness pathology degrades to sc1 speed, not a hang.
//   (c) absolute bound 2^16 trips: degrade to terminating-but-wrong
//       (bench fails with counters instead of hanging the device).
//
// Slot ring R=64, owner-zeroed at (i-2): I stored row i => I completed poll
// of row i-1 => all blocks stored row i-1 => all finished reading row i-2.
// Election state lives in the UNUSED tail u64s (offset +1 of each 64B slot)
// of ring rows 61..63; protocol reuse of those rows happens ~60 iterations
// later when the election data is dead.
//   row 61 tails: hs[w]  (sc0 handshake tokens, workers only)
//   row 62 tails: ok[w]  (sc1 outcome exchange, workers only)
//   row 63 tails: cnt[x] x<8 (slots 0..7), winner (slot 8)  (sc1, all blocks)
#define FPS_NB    14
#define FPS_GRID  128    // 8 XCDs * 16; pigeonhole: some XCD gets >= 14 blocks
#define FPS_NT    512
#define FPS_PPT   7      // 112 waves * 64 * 7 = 50176 >= 50000
#define FPS_R     64     // ring depth (power of 2)
#define SLOT_U64  8      // 64B stride: one cache line per block slot
#define ROW_U64   (FPS_NB*SLOT_U64)   // 112 u64 per ring row
#define FPS_FAST_TRIPS 512            // pure-sc0 probe budget per poll
#define FPS_POLL_BOUND (1<<16)        // absolute insurance; never hit if healthy

__global__ void init_ws_kernel(u64* __restrict__ slots) {
  int t = blockIdx.x * blockDim.x + threadIdx.x;
  if (t < FPS_R * FPS_NB * SLOT_U64) slots[t] = 0ull;
}

// ---- XCD-L2-served plain accesses (sc0 = L1 force-miss / write-through) ----
__device__ __forceinline__ u64 fast_load(const u64* p) {
  u64 v;
  asm volatile("global_load_dwordx2 %0, %1, off sc0\n\ts_waitcnt vmcnt(0)"
               : "=v"(v) : "v"(p) : "memory");
  return v;
}
__device__ __forceinline__ void fast_store(u64* p, u64 v) {
  asm volatile("global_store_dwordx2 %0, %1, off sc0"
               :: "v"(p), "v"(v) : "memory");
}
__device__ __forceinline__ u64 sc1_load(const u64* p) {
  return __hip_atomic_load(p, __ATOMIC_RELAXED, __HIP_MEMORY_SCOPE_AGENT);
}
template <bool SAFE>
__device__ __forceinline__ u64 slot_load(const u64* p) {
  if (SAFE) return sc1_load(p);
  return fast_load(p);
}
template <bool SAFE>
__device__ __forceinline__ void slot_store(u64* p, u64 v) {
  if (SAFE) __hip_atomic_store(p, v, __ATOMIC_RELAXED, __HIP_MEMORY_SCOPE_AGENT);
  else      fast_store(p, v);
}

// ---- DPP wave-wide reductions (ctrl must be a literal constant) ----
template <int CTRL>
__device__ __forceinline__ u32 dppmov_u(u32 v) {
  return (u32)__builtin_amdgcn_update_dpp((int)v, (int)v, CTRL, 0xf, 0xf, false);
}
template <int CTRL>
__device__ __forceinline__ float dppmov_f(float v) {
  return __int_as_float(
      __builtin_amdgcn_update_dpp(__float_as_int(v), __float_as_int(v),
                                  CTRL, 0xf, 0xf, false));
}
__device__ __forceinline__ float wave_max_f32(float v) {
  v = fmaxf(v, dppmov_f<0x111>(v));   // row_shr:1
  v = fmaxf(v, dppmov_f<0x112>(v));   // row_shr:2
  v = fmaxf(v, dppmov_f<0x114>(v));   // row_shr:4
  v = fmaxf(v, dppmov_f<0x118>(v));   // row_shr:8
  v = fmaxf(v, dppmov_f<0x142>(v));   // row_bcast:15
  v = fmaxf(v, dppmov_f<0x143>(v));   // row_bcast:31
  return __int_as_float(__builtin_amdgcn_readlane(__float_as_int(v), 63));
}
__device__ __forceinline__ u32 wave_max_u32(u32 v) {
  u32 t;
  t = dppmov_u<0x111>(v); v = v > t ? v : t;
  t = dppmov_u<0x112>(v); v = v > t ? v : t;
  t = dppmov_u<0x114>(v); v = v > t ? v : t;
  t = dppmov_u<0x118>(v); v = v > t ? v : t;
  t = dppmov_u<0x142>(v); v = v > t ? v : t;
  t = dppmov_u<0x143>(v); v = v > t ? v : t;
  return (u32)__builtin_amdgcn_readlane((int)v, 63);
}
__device__ __forceinline__ u32 wave_min_u32(u32 v) {
  u32 t;
  t = dppmov_u<0x111>(v); v = v < t ? v : t;
  t = dppmov_u<0x112>(v); v = v < t ? v : t;
  t = dppmov_u<0x114>(v); v = v < t ? v : t;
  t = dppmov_u<0x118>(v); v = v < t ? v : t;
  t = dppmov_u<0x142>(v); v = v < t ? v : t;
  t = dppmov_u<0x143>(v); v = v < t ? v : t;
  return (u32)__builtin_amdgcn_readlane((int)v, 63);
}

template <bool SAFE>
__device__ __forceinline__ void fps_main(
    const float* __restrict__ pos, u64* __restrict__ slots,
    float* __restrict__ cent_out, const int wid,
    uint2 (*s_w)[FPS_NT/64], float (*s_bc)[3])
{
  const int lane = threadIdx.x & 63;
  const int wv   = threadIdx.x >> 6;          // 0..7
  const int w    = wid * (FPS_NT/64) + wv;    // global wave 0..111

  float px[FPS_PPT], py[FPS_PPT], pz[FPS_PPT], dist[FPS_PPT];
#pragma unroll
  for (int j = 0; j < FPS_PPT; j++) {
    int n = (w * FPS_PPT + j) * 64 + lane;
    if (n < N_PTS) {
      px[j] = pos[3*n+0]; py[j] = pos[3*n+1]; pz[j] = pos[3*n+2];
      dist[j] = FLT_MAX;               // matches finfo(f32).max init
    } else {
      px[j] = 0.f; py[j] = 0.f; pz[j] = 0.f; dist[j] = -1.f;  // never wins
    }
  }

  bool broken = false;   // fast-mode insurance flag (leader-wave lanes only)

  // iteration 0 centroid = point 0 (deterministic start, matches reference)
  float cx = pos[0], cy = pos[1], cz = pos[2];

  for (int i = 0; i < M_CENT; i++) {
    if (wid == 0 && wv == 0 && lane == 0) {
      cent_out[3*i+0] = cx; cent_out[3*i+1] = cy; cent_out[3*i+2] = cz;
    }
    // phase 1: update dists, track lane-local max value only
    float lmax = -1.0f;
#pragma unroll
    for (int j = 0; j < FPS_PPT; j++) {
      int n = (w * FPS_PPT + j) * 64 + lane;
      if (n < N_PTS) {
        // exact reference arithmetic: no FMA contraction, ((dx^2+dy^2)+dz^2)
        float dx = __fsub_rn(px[j], cx);
        float dy = __fsub_rn(py[j], cy);
        float dz = __fsub_rn(pz[j], cz);
        float d2 = __fadd_rn(__fadd_rn(__fmul_rn(dx,dx), __fmul_rn(dy,dy)),
                             __fmul_rn(dz,dz));
        float d  = fminf(dist[j], d2);
        dist[j] = d;
        lmax = fmaxf(lmax, d);
      }
    }
    // phase 2: wave max dist (DPP), then min index among ties (DPP)
    float wmax = wave_max_f32(lmax);   // >= 0 (dists >= 0; lmax=-1 never wins)
    u32 li = 0xFFFFFFFFu;
#pragma unroll
    for (int j = 0; j < FPS_PPT; j++) {
      int n = (w * FPS_PPT + j) * 64 + lane;
      if (n < N_PTS && dist[j] == wmax) li = li < (u32)n ? li : (u32)n;
    }
    u32 widx = wave_min_u32(li);

    if (i == M_CENT - 1) break;   // last winner never consumed

    if (lane == 0) s_w[i & 1][wv] = make_uint2(__float_as_uint(wmax), widx);
    __syncthreads();

    if (wv == 0) {
      // ---- leader wave: block reduce + store + poll + winner select ----
      uint2 kv = (lane < FPS_NT/64) ? s_w[i & 1][lane]
                                    : make_uint2(0u, 0xFFFFFFFFu);
      // dist bits are IEEE >= 0 -> u32 order == float order
      u32 bmaxb = wave_max_u32(kv.x);
      u32 bidx  = wave_min_u32(kv.x == bmaxb ? kv.y : 0xFFFFFFFFu);
      u64 ownkey = ((u64)bmaxb << 32) | (u64)(0xFFFFFFFFu - bidx);
      u64* row = slots + (size_t)(i & (FPS_R-1)) * ROW_U64;

      u64 got;
      if (!SAFE && broken) {
        // degraded (insurance tripped): terminate with own-block winner
        got = (lane == wid) ? ownkey : 1ull;
      } else {
        if (lane == 0) {
          slot_store<SAFE>(&row[wid * SLOT_U64], ownkey);
          if (i >= 2)   // retire own slot in row (i-2); safe per header proof
            slot_store<SAFE>(&slots[(size_t)((i-2) & (FPS_R-1)) * ROW_U64
                                    + wid * SLOT_U64], 0ull);
        }
        // poll: lane l (l < 14) waits on slot l; single probe per trip.
        // Fast mode: sc0 probes; after FPS_FAST_TRIPS fruitless trips every
        // 4th probe is an sc1 agent load (staleness-proof recovery path).
        got = (lane < FPS_NB) ? 0ull : 1ull;
        u64* sl = row + lane * SLOT_U64;
        int trips = 0;
        while (__ballot(got == 0ull)) {
          if (got == 0ull) {
            if (SAFE) got = sc1_load(sl);
            else if (trips < FPS_FAST_TRIPS || (trips & 3)) got = fast_load(sl);
            else got = sc1_load(sl);
          }
          if (!SAFE) {
            if (++trips > FPS_POLL_BOUND) {        // never hit if healthy
              if (got == 0ull) got = 1ull;
              broken = true;
            }
          }
        }
      }
      u32 hi = (u32)(got >> 32), lo = (u32)got;
      // candidate-coord prefetch, overlapped with the winner DPP chains
      u32 ic = 0xFFFFFFFFu - lo;
      if (ic >= N_PTS) ic = 0;   // OOB guard (impossible when healthy)
      float qx = 0.f, qy = 0.f, qz = 0.f;
      if (lane < FPS_NB) { qx = pos[3*ic]; qy = pos[3*ic+1]; qz = pos[3*ic+2]; }

      u32 H  = wave_max_u32(lane < FPS_NB ? hi : 0u);
      u32 LO = wave_max_u32((lane < FPS_NB && hi == H) ? lo : 0u); // lo=~idx
      u64 msk = __ballot(lane < FPS_NB && hi == H && lo == LO);    // unique
      int L = __ffsll((long long)msk) - 1;
      float ncx = __int_as_float(__builtin_amdgcn_readlane(__float_as_int(qx), L));
      float ncy = __int_as_float(__builtin_amdgcn_readlane(__float_as_int(qy), L));
      float ncz = __int_as_float(__builtin_amdgcn_readlane(__float_as_int(qz), L));
      if (lane == 0) {
        s_bc[i & 1][0] = ncx; s_bc[i & 1][1] = ncy; s_bc[i & 1][2] = ncz;
      }
    }
    __syncthreads();
    cx = s_bc[i & 1][0]; cy = s_bc[i & 1][1]; cz = s_bc[i & 1][2];
  }
}

__global__ __launch_bounds__(FPS_NT) void fps_kernel(
    const float* __restrict__ pos,
    u64* __restrict__ slots,       // [FPS_R][FPS_NB][SLOT_U64], zeroed
    float* __restrict__ cent_out)  // d_out[0 .. 3*M_CENT)
{
  __shared__ uint2 s_w[2][FPS_NT/64];   // per-wave (dist bits, idx), dbl-buf
  __shared__ float s_bc[2][3];          // winner coords broadcast
  __shared__ int   s_role[2];           // [0]=worker id or -1, [1]=safe mode

  if (threadIdx.x == 0) {
    u32 xcc;
    asm volatile("s_getreg_b32 %0, hwreg(HW_REG_XCC_ID, 0, 4)" : "=s"(xcc));
    xcc &= 7u;   // 8 counters; pigeonhole over 128 blocks => some cnt >= 14
    u64* cntp = slots + 63*ROW_U64 + (size_t)xcc * SLOT_U64 + 1;
    u64* winp = slots + 63*ROW_U64 + 8 * SLOT_U64 + 1;
    u64 t = __hip_atomic_fetch_add(cntp, 1ull, __ATOMIC_RELAXED,
                                   __HIP_MEMORY_SCOPE_AGENT);
    int ticket = (int)t;
    if (ticket == FPS_NB - 1) {
      // 14th block on this XCD: claim the job (first claimant wins)
      u64 exp = 0ull;
      __hip_atomic_compare_exchange_strong(winp, &exp, (u64)(xcc + 1),
          __ATOMIC_RELAXED, __ATOMIC_RELAXED, __HIP_MEMORY_SCOPE_AGENT);
    }
    int role = -1, safe = 0;
    if (ticket < FPS_NB) {
      u64 win;
      do {   // guaranteed set: total 128 > 8*13, so some XCD reaches ticket 13
        win = __hip_atomic_load(winp, __ATOMIC_RELAXED, __HIP_MEMORY_SCOPE_AGENT);
        if (win == 0ull) __builtin_amdgcn_s_sleep(1);
      } while (win == 0ull);
      if (win == (u64)(xcc + 1)) {
        role = ticket;
        // ---- handshake over the FAST primitive (sc0), bounded ----
        // Exercises the exact staleness scenario: sc0 stores from 14 CUs
        // observed by sc0 loads from 14 other CUs, repeatedly.
        u64* hs = slots + 61*ROW_U64;
        fast_store(hs + (size_t)role * SLOT_U64 + 1, 1ull);
        bool okk = false;
        for (int trip = 0; trip < 512 && !okk; ++trip) {
          int seen = 0;
          for (int j = 0; j < FPS_NB; ++j)
            seen += (fast_load(hs + (size_t)j * SLOT_U64 + 1) != 0ull);
          okk = (seen == FPS_NB);
          if (!okk) __builtin_amdgcn_s_sleep(8);
        }
        // unanimous fast/safe decision over the always-coherent sc1 channel
        u64* okp = slots + 62*ROW_U64;
        __hip_atomic_store(okp + (size_t)role * SLOT_U64 + 1,
                           okk ? 2ull : 1ull,
                           __ATOMIC_RELAXED, __HIP_MEMORY_SCOPE_AGENT);
        for (int j = 0; j < FPS_NB; ++j) {   // all 14 write -> terminates
          u64 v;
          do {
            v = __hip_atomic_load(okp + (size_t)j * SLOT_U64 + 1,
                                  __ATOMIC_RELAXED, __HIP_MEMORY_SCOPE_AGENT);
            if (v == 0ull) __builtin_amdgcn_s_sleep(1);
          } while (v == 0ull);
          if (v == 1ull) safe = 1;   // any timeout => everyone goes safe
        }
      }
    }
    s_role[0] = role; s_role[1] = safe;
  }
  __syncthreads();
  const int wid = s_role[0];
  if (wid < 0) return;               // non-elected block: done
  if (s_role[1]) fps_main<true >(pos, slots, cent_out, wid, s_w, s_bc);
  else           fps_main<false>(pos, slots, cent_out, wid, s_w, s_bc);
}

// ---------------- Ball query ----------------
#define BQ_NT  256
#define BQ_CAP 2048   // expected ~209 candidates/centroid; huge safety margin

__global__ __launch_bounds__(BQ_NT) void ballq_kernel(
    const float* __restrict__ pos,
    const float* __restrict__ cent,   // centroid coords (from d_out)
    int* __restrict__ nbr,            // [M_CENT*K_LOC]
    int* __restrict__ nsel)           // [M_CENT]
{
  __shared__ float s_d2[BQ_CAP];
  __shared__ int   s_idx[BQ_CAP];
  __shared__ int   s_count;
  __shared__ u64   s_red[BQ_NT/64];
  __shared__ u64   s_win;

  const int m = blockIdx.x, tid = threadIdx.x;
  if (tid == 0) s_count = 0;
  __syncthreads();
  const float cx = cent[3*m+0], cy = cent[3*m+1], cz = cent[3*m+2];

  for (int n = tid; n < N_PTS; n += BQ_NT) {
    float dx = __fsub_rn(cx, pos[3*n+0]);
    float dy = __fsub_rn(cy, pos[3*n+1]);
    float dz = __fsub_rn(cz, pos[3*n+2]);
    float d2 = __fadd_rn(__fadd_rn(__fmul_rn(dx,dx), __fmul_rn(dy,dy)),
                         __fmul_rn(dz,dz));
    if (d2 <= 0.01f) {   // same f32 value as (float)(0.1*0.1)
      int p = atomicAdd(&s_count, 1);
      if (p < BQ_CAP) { s_d2[p] = d2; s_idx[p] = n; }
    }
  }
  __syncthreads();
  int cnt = s_count; if (cnt > BQ_CAP) cnt = BQ_CAP;
  int ns = cnt < K_LOC ? cnt : K_LOC;

  // exact top_k semantics: k smallest d2, ties -> smaller index
  for (int sel = 0; sel < ns; sel++) {
    u64 best = ~0ull;
    for (int p = tid; p < cnt; p += BQ_NT) {
      u64 pk = ((u64)__float_as_uint(s_d2[p]) << 32) | (u64)(u32)s_idx[p];
      if (pk < best) best = pk;
    }
#pragma unroll
    for (int off = 32; off >= 1; off >>= 1) {
      u64 o = __shfl_down(best, off, 64);
      if (o < best) best = o;
    }
    if ((tid & 63) == 0) s_red[tid >> 6] = best;
    __syncthreads();
    if (tid < 64) {
      best = (tid < BQ_NT/64) ? s_red[tid] : ~0ull;
#pragma unroll
      for (int off = 2; off >= 1; off >>= 1) {
        u64 o = __shfl_down(best, off, 64);
        if (o < best) best = o;
      }
      if (tid == 0) s_win = best;
    }
    __syncthreads();
    int widx = (int)(u32)(s_win & 0xFFFFFFFFull);
    if (tid == 0) nbr[m*K_LOC + sel] = widx;
    for (int p = tid; p < cnt; p += BQ_NT) {
      if (s_idx[p] == widx) s_d2[p] = FLT_MAX;   // remove winner
    }
    __syncthreads();
  }
  if (tid == 0) nsel[m] = ns;
}

// ---------------- Gather + max-pool + channel mix ----------------
// Max over the valid selected set == reference (fallback idx is the nearest
// valid neighbor, already a member of the set).
__global__ __launch_bounds__(C_CH) void pool_mix_kernel(
    const float* __restrict__ fs,   // (N,128,1)
    const float* __restrict__ fv,   // (N,128,3)
    const float* __restrict__ Ws,
    const float* __restrict__ Wv,
    const float* __restrict__ bs,
    const float* __restrict__ bv,
    const int* __restrict__ nbr,
    const int* __restrict__ nsel,
    float* __restrict__ out_s,      // (M,128,1)
    float* __restrict__ out_v)      // (M,128,3)
{
  __shared__ float ps[C_CH];
  __shared__ float pv[C_CH*3];
  const int m = blockIdx.x, o = threadIdx.x;
  const int ns = nsel[m];
  float mS = -FLT_MAX, m0 = -FLT_MAX, m1 = -FLT_MAX, m2 = -FLT_MAX;
  for (int j = 0; j < ns; j++) {
    int n = nbr[m*K_LOC + j];
    mS = fmaxf(mS, fs[(size_t)n*C_CH + o]);
    const float* r = fv + (size_t)n*(C_CH*3) + 3*o;
    m0 = fmaxf(m0, r[0]); m1 = fmaxf(m1, r[1]); m2 = fmaxf(m2, r[2]);
  }
  ps[o] = mS; pv[3*o+0] = m0; pv[3*o+1] = m1; pv[3*o+2] = m2;
  __syncthreads();
  float aS = bs[o];
  float a0 = bv[o], a1 = bv[o], a2 = bv[o];
  for (int cc = 0; cc < C_CH; cc++) {
    float w1 = Ws[cc*C_CH + o];
    float w2 = Wv[cc*C_CH + o];
    aS = fmaf(ps[cc], w1, aS);
    a0 = fmaf(pv[3*cc+0], w2, a0);
    a1 = fmaf(pv[3*cc+1], w2, a1);
    a2 = fmaf(pv[3*cc+2], w2, a2);
  }
  out_s[(size_t)m*C_CH + o] = aS;
  float* ov = out_v + (size_t)m*(C_CH*3) + 3*o;
  ov[0] = a0; ov[1] = a1; ov[2] = a2;
}

extern "C" void kernel_launch(void* const* d_in, const int* in_sizes, int n_in,
                              void* d_out, int out_size, void* d_ws, size_t ws_size,
                              hipStream_t stream) {
  (void)in_sizes; (void)n_in; (void)out_size; (void)ws_size;
  const float* pos = (const float*)d_in[0];
  const float* fs  = (const float*)d_in[1];
  const float* fv  = (const float*)d_in[2];
  const float* Ws  = (const float*)d_in[3];
  const float* Wv  = (const float*)d_in[4];
  const float* bs  = (const float*)d_in[5];
  const float* bv  = (const float*)d_in[6];

  float* out      = (float*)d_out;
  float* cent_out = out;                               // 2048*3
  float* out_s    = out + 3*M_CENT;                    // 2048*128
  float* out_v    = out + 3*M_CENT + M_CENT*C_CH;      // 2048*128*3

  char* ws = (char*)d_ws;
  u64* slots = (u64*)ws;                               // 64*14*8*8B = 57344 B
  size_t slots_bytes = (size_t)FPS_R * FPS_NB * SLOT_U64 * 8;
  int* nbr   = (int*)(ws + slots_bytes);               // 256 KB
  int* nsel  = (int*)(ws + slots_bytes + (size_t)M_CENT*K_LOC*4);

  init_ws_kernel<<<(FPS_R*FPS_NB*SLOT_U64 + 255)/256, 256, 0, stream>>>(slots);
  fps_kernel<<<FPS_GRID, FPS_NT, 0, stream>>>(pos, slots, cent_out);
  ballq_kernel<<<M_CENT, BQ_NT, 0, stream>>>(pos, cent_out, nbr, nsel);
  pool_mix_kernel<<<M_CENT, C_CH, 0, stream>>>(fs, fv, Ws, Wv, bs, bv,
                                               nbr, nsel, out_s, out_v);
}

// Round 4
// 3663.452 us; speedup vs baseline: 31.2171x; 31.2171x over previous
//
#include <hip/hip_runtime.h>
#include <float.h>

#define N_PTS   50000
#define M_CENT  2048
#define K_LOC   32
#define C_CH    128

typedef unsigned long long u64;
typedef unsigned int u32;

// ---------------- FPS ----------------
// 14 worker blocks x 512, leader-wave-only polling, DPP reductions. Workers
// ELECTED onto one XCD via HW_REG_XCC_ID (proven working R2/R3).
//
// Measured primitive facts (R2/R3 on this chip):
//  - global atomics (any sc flags) execute at memory-side units: fabric
//    latency + one HBM write each (R2: WRITE_SIZE 18 MB). No L2 atomics.
//  - plain sc0 LOAD does NOT bypass vL1: serves stale data forever (R3:
//    every poll needed the sc1 recovery, 83 us/iter).
//  - sc0 STORE is visible to sc1 loads (R3 passed with absmax 0) -> sc0
//    stores reach at least the local L2 / coherence path.
// => fast probe must be: invalidate vL1, then plain load (misses L1, hits
//    the XCD-shared L2 where co-located writers' sc0 stores land):
//        buffer_inv sc0 ; global_load_dwordx2 ; s_waitcnt vmcnt(0)
//
// Correctness ladder (no HW surprise can hang or corrupt):
//  (a) 3-round handshake over the EXACT fast primitives; rounds 2/3 defeat
//      any cached round-(r-1) line (catches R3's false-pass). Bounded; any
//      timeout -> unanimous (sc1-exchanged) fallback to the proven
//      agent-scope protocol (R0: 4078 us).
//  (b) fast main-loop poll bounded at FPS_FAST_TRIPS; on failure sets a
//      STICKY distrust flag (leader-local) -> all later iterations go
//      straight to sc1 probes (sc1 sees sc0 data, R3-proven). One-time
//      ~30 us penalty, no per-iteration repeat.
//  (c) absolute bound on the sc1 poll: degrade to terminating-but-wrong
//      rather than hanging the device (never hit if healthy).
//
// Slot ring R=64, owner-zeroed at (i-2): I stored row i => I completed poll
// of row i-1 => all blocks stored row i-1 => all finished reading row i-2.
// Election state lives in the UNUSED tail u64s (offset +1 of each 64B slot)
// of ring rows 61..63; protocol keys live at offset +0, so tokens never
// alias keys, and row reuse happens ~60 iterations after election death.
//   row 61 tails: hs[w]  (fast-primitive handshake tokens, workers only)
//   row 62 tails: ok[w]  (sc1 outcome exchange, workers only)
//   row 63 tails: cnt[x] x<8 (slots 0..7), winner (slot 8)  (sc1, all blocks)
#define FPS_NB    14
#define FPS_GRID  128    // 8 XCDs * 16; pigeonhole: some XCD gets >= 14 blocks
#define FPS_NT    512
#define FPS_PPT   7      // 112 waves * 64 * 7 = 50176 >= 50000
#define FPS_R     64     // ring depth (power of 2)
#define SLOT_U64  8      // 64B stride: one cache line per block slot
#define ROW_U64   (FPS_NB*SLOT_U64)   // 112 u64 per ring row
#define FPS_FAST_TRIPS 256            // fast-probe budget before sticky distrust
#define FPS_POLL_BOUND (1<<16)        // absolute insurance; never hit if healthy

__global__ void init_ws_kernel(u64* __restrict__ slots) {
  int t = blockIdx.x * blockDim.x + threadIdx.x;
  if (t < FPS_R * FPS_NB * SLOT_U64) slots[t] = 0ull;
}

// ---- fast primitives: sc0 store (lands in local L2), inv'd plain load ----
__device__ __forceinline__ void fast_store(u64* p, u64 v) {
  asm volatile("global_store_dwordx2 %0, %1, off sc0"
               :: "v"(p), "v"(v) : "memory");
}
__device__ __forceinline__ u64 fresh_load(const u64* p) {
  u64 v;
  asm volatile("buffer_inv sc0\n\t"            // invalidate vL1 (this CU)
               "global_load_dwordx2 %0, %1, off\n\t"
               "s_waitcnt vmcnt(0)"
               : "=v"(v) : "v"(p) : "memory");
  return v;
}
__device__ __forceinline__ u64 sc1_load(const u64* p) {
  return __hip_atomic_load(p, __ATOMIC_RELAXED, __HIP_MEMORY_SCOPE_AGENT);
}
template <bool SAFE>
__device__ __forceinline__ void slot_store(u64* p, u64 v) {
  if (SAFE) __hip_atomic_store(p, v, __ATOMIC_RELAXED, __HIP_MEMORY_SCOPE_AGENT);
  else      fast_store(p, v);
}

// ---- DPP wave-wide reductions (ctrl must be a literal constant) ----
template <int CTRL>
__device__ __forceinline__ u32 dppmov_u(u32 v) {
  return (u32)__builtin_amdgcn_update_dpp((int)v, (int)v, CTRL, 0xf, 0xf, false);
}
template <int CTRL>
__device__ __forceinline__ float dppmov_f(float v) {
  return __int_as_float(
      __builtin_amdgcn_update_dpp(__float_as_int(v), __float_as_int(v),
                                  CTRL, 0xf, 0xf, false));
}
__device__ __forceinline__ float wave_max_f32(float v) {
  v = fmaxf(v, dppmov_f<0x111>(v));   // row_shr:1
  v = fmaxf(v, dppmov_f<0x112>(v));   // row_shr:2
  v = fmaxf(v, dppmov_f<0x114>(v));   // row_shr:4
  v = fmaxf(v, dppmov_f<0x118>(v));   // row_shr:8
  v = fmaxf(v, dppmov_f<0x142>(v));   // row_bcast:15
  v = fmaxf(v, dppmov_f<0x143>(v));   // row_bcast:31
  return __int_as_float(__builtin_amdgcn_readlane(__float_as_int(v), 63));
}
__device__ __forceinline__ u32 wave_max_u32(u32 v) {
  u32 t;
  t = dppmov_u<0x111>(v); v = v > t ? v : t;
  t = dppmov_u<0x112>(v); v = v > t ? v : t;
  t = dppmov_u<0x114>(v); v = v > t ? v : t;
  t = dppmov_u<0x118>(v); v = v > t ? v : t;
  t = dppmov_u<0x142>(v); v = v > t ? v : t;
  t = dppmov_u<0x143>(v); v = v > t ? v : t;
  return (u32)__builtin_amdgcn_readlane((int)v, 63);
}
__device__ __forceinline__ u32 wave_min_u32(u32 v) {
  u32 t;
  t = dppmov_u<0x111>(v); v = v < t ? v : t;
  t = dppmov_u<0x112>(v); v = v < t ? v : t;
  t = dppmov_u<0x114>(v); v = v < t ? v : t;
  t = dppmov_u<0x118>(v); v = v < t ? v : t;
  t = dppmov_u<0x142>(v); v = v < t ? v : t;
  t = dppmov_u<0x143>(v); v = v < t ? v : t;
  return (u32)__builtin_amdgcn_readlane((int)v, 63);
}

template <bool SAFE>
__device__ __forceinline__ void fps_main(
    const float* __restrict__ pos, u64* __restrict__ slots,
    float* __restrict__ cent_out, const int wid,
    uint2 (*s_w)[FPS_NT/64], float (*s_bc)[3])
{
  const int lane = threadIdx.x & 63;
  const int wv   = threadIdx.x >> 6;          // 0..7
  const int w    = wid * (FPS_NT/64) + wv;    // global wave 0..111

  float px[FPS_PPT], py[FPS_PPT], pz[FPS_PPT], dist[FPS_PPT];
#pragma unroll
  for (int j = 0; j < FPS_PPT; j++) {
    int n = (w * FPS_PPT + j) * 64 + lane;
    if (n < N_PTS) {
      px[j] = pos[3*n+0]; py[j] = pos[3*n+1]; pz[j] = pos[3*n+2];
      dist[j] = FLT_MAX;               // matches finfo(f32).max init
    } else {
      px[j] = 0.f; py[j] = 0.f; pz[j] = 0.f; dist[j] = -1.f;  // never wins
    }
  }

  bool broken   = false;  // absolute-insurance flag (leader-wave only)
  bool distrust = false;  // sticky: fast probes failed once -> sc1 forever

  // iteration 0 centroid = point 0 (deterministic start, matches reference)
  float cx = pos[0], cy = pos[1], cz = pos[2];

  for (int i = 0; i < M_CENT; i++) {
    if (wid == 0 && wv == 0 && lane == 0) {
      cent_out[3*i+0] = cx; cent_out[3*i+1] = cy; cent_out[3*i+2] = cz;
    }
    // phase 1: update dists, track lane-local max value only
    float lmax = -1.0f;
#pragma unroll
    for (int j = 0; j < FPS_PPT; j++) {
      int n = (w * FPS_PPT + j) * 64 + lane;
      if (n < N_PTS) {
        // exact reference arithmetic: no FMA contraction, ((dx^2+dy^2)+dz^2)
        float dx = __fsub_rn(px[j], cx);
        float dy = __fsub_rn(py[j], cy);
        float dz = __fsub_rn(pz[j], cz);
        float d2 = __fadd_rn(__fadd_rn(__fmul_rn(dx,dx), __fmul_rn(dy,dy)),
                             __fmul_rn(dz,dz));
        float d  = fminf(dist[j], d2);
        dist[j] = d;
        lmax = fmaxf(lmax, d);
      }
    }
    // phase 2: wave max dist (DPP), then min index among ties (DPP)
    float wmax = wave_max_f32(lmax);   // >= 0 (dists >= 0; lmax=-1 never wins)
    u32 li = 0xFFFFFFFFu;
#pragma unroll
    for (int j = 0; j < FPS_PPT; j++) {
      int n = (w * FPS_PPT + j) * 64 + lane;
      if (n < N_PTS && dist[j] == wmax) li = li < (u32)n ? li : (u32)n;
    }
    u32 widx = wave_min_u32(li);

    if (i == M_CENT - 1) break;   // last winner never consumed

    if (lane == 0) s_w[i & 1][wv] = make_uint2(__float_as_uint(wmax), widx);
    __syncthreads();

    if (wv == 0) {
      // ---- leader wave: block reduce + store + poll + winner select ----
      uint2 kv = (lane < FPS_NT/64) ? s_w[i & 1][lane]
                                    : make_uint2(0u, 0xFFFFFFFFu);
      // dist bits are IEEE >= 0 -> u32 order == float order
      u32 bmaxb = wave_max_u32(kv.x);
      u32 bidx  = wave_min_u32(kv.x == bmaxb ? kv.y : 0xFFFFFFFFu);
      u64 ownkey = ((u64)bmaxb << 32) | (u64)(0xFFFFFFFFu - bidx);  // != 0
      u64* row = slots + (size_t)(i & (FPS_R-1)) * ROW_U64;

      u64 got;
      if (!SAFE && broken) {
        // degraded (insurance tripped): terminate with own-block winner
        got = (lane == wid) ? ownkey : 1ull;
      } else {
        if (lane == 0) {
          slot_store<SAFE>(&row[wid * SLOT_U64], ownkey);
          if (i >= 2)   // retire own slot in row (i-2); safe per header proof
            slot_store<SAFE>(&slots[(size_t)((i-2) & (FPS_R-1)) * ROW_U64
                                    + wid * SLOT_U64], 0ull);
        }
        // poll: lane l (l < 14) waits on slot l; single probe per trip
        got = (lane < FPS_NB) ? 0ull : 1ull;
        u64* sl = row + lane * SLOT_U64;
        if (!SAFE) {
          if (!distrust) {
            int t = 0;
            while (__ballot(got == 0ull) && t < FPS_FAST_TRIPS) {
              if (got == 0ull) got = fresh_load(sl);
              ++t;
            }
            if (__ballot(got == 0ull)) distrust = true;   // sticky, one-time
          }
          int trips = 0;
          while (__ballot(got == 0ull)) {
            if (got == 0ull) got = sc1_load(sl);   // sees sc0 data (R3-proven)
            if (++trips > FPS_POLL_BOUND) {        // never hit if healthy
              if (got == 0ull) got = 1ull;
              broken = true;
            }
          }
        } else {
          while (__ballot(got == 0ull)) {
            if (got == 0ull) got = sc1_load(sl);
          }
        }
      }
      u32 hi = (u32)(got >> 32), lo = (u32)got;
      // candidate-coord prefetch, overlapped with the winner DPP chains
      u32 ic = 0xFFFFFFFFu - lo;
      if (ic >= N_PTS) ic = 0;   // OOB guard (impossible when healthy)
      float qx = 0.f, qy = 0.f, qz = 0.f;
      if (lane < FPS_NB) { qx = pos[3*ic]; qy = pos[3*ic+1]; qz = pos[3*ic+2]; }

      u32 H  = wave_max_u32(lane < FPS_NB ? hi : 0u);
      u32 LO = wave_max_u32((lane < FPS_NB && hi == H) ? lo : 0u); // lo=~idx
      u64 msk = __ballot(lane < FPS_NB && hi == H && lo == LO);    // unique
      int L = __ffsll((long long)msk) - 1;
      float ncx = __int_as_float(__builtin_amdgcn_readlane(__float_as_int(qx), L));
      float ncy = __int_as_float(__builtin_amdgcn_readlane(__float_as_int(qy), L));
      float ncz = __int_as_float(__builtin_amdgcn_readlane(__float_as_int(qz), L));
      if (lane == 0) {
        s_bc[i & 1][0] = ncx; s_bc[i & 1][1] = ncy; s_bc[i & 1][2] = ncz;
      }
    }
    __syncthreads();
    cx = s_bc[i & 1][0]; cy = s_bc[i & 1][1]; cz = s_bc[i & 1][2];
  }
}

__global__ __launch_bounds__(FPS_NT) void fps_kernel(
    const float* __restrict__ pos,
    u64* __restrict__ slots,       // [FPS_R][FPS_NB][SLOT_U64], zeroed
    float* __restrict__ cent_out)  // d_out[0 .. 3*M_CENT)
{
  __shared__ uint2 s_w[2][FPS_NT/64];   // per-wave (dist bits, idx), dbl-buf
  __shared__ float s_bc[2][3];          // winner coords broadcast
  __shared__ int   s_role[2];           // [0]=worker id or -1, [1]=safe mode

  if (threadIdx.x == 0) {
    u32 xcc;
    asm volatile("s_getreg_b32 %0, hwreg(HW_REG_XCC_ID, 0, 4)" : "=s"(xcc));
    xcc &= 7u;   // 8 counters; pigeonhole over 128 blocks => some cnt >= 14
    u64* cntp = slots + 63*ROW_U64 + (size_t)xcc * SLOT_U64 + 1;
    u64* winp = slots + 63*ROW_U64 + 8 * SLOT_U64 + 1;
    u64 t = __hip_atomic_fetch_add(cntp, 1ull, __ATOMIC_RELAXED,
                                   __HIP_MEMORY_SCOPE_AGENT);
    int ticket = (int)t;
    if (ticket == FPS_NB - 1) {
      // 14th block on this XCD: claim the job (first claimant wins)
      u64 exp = 0ull;
      __hip_atomic_compare_exchange_strong(winp, &exp, (u64)(xcc + 1),
          __ATOMIC_RELAXED, __ATOMIC_RELAXED, __HIP_MEMORY_SCOPE_AGENT);
    }
    int role = -1, safe = 0;
    if (ticket < FPS_NB) {
      u64 win;
      do {   // guaranteed set: total 128 > 8*13, so some XCD reaches ticket 13
        win = __hip_atomic_load(winp, __ATOMIC_RELAXED, __HIP_MEMORY_SCOPE_AGENT);
        if (win == 0ull) __builtin_amdgcn_s_sleep(1);
      } while (win == 0ull);
      if (win == (u64)(xcc + 1)) {
        role = ticket;
        // ---- 3-round handshake over the FAST primitives, bounded ----
        // Rounds 2/3 poll lines already cached from round r-1: passes ONLY
        // if buffer_inv genuinely refreshes them (catches R3's false-pass).
        u64* hs = slots + 61*ROW_U64;
        bool okk = true;
        for (int r = 1; r <= 3 && okk; ++r) {
          fast_store(hs + (size_t)role * SLOT_U64 + 1, (u64)r);
          bool seen_all = false;
          for (int trip = 0; trip < 128 && !seen_all; ++trip) {
            int seen = 0;
            for (int j = 0; j < FPS_NB; ++j)
              seen += (fresh_load(hs + (size_t)j * SLOT_U64 + 1) >= (u64)r);
            seen_all = (seen == FPS_NB);
            if (!seen_all) __builtin_amdgcn_s_sleep(4);
          }
          okk = seen_all;
        }
        // unanimous fast/safe decision over the always-coherent sc1 channel
        u64* okp = slots + 62*ROW_U64;
        __hip_atomic_store(okp + (size_t)role * SLOT_U64 + 1,
                           okk ? 2ull : 1ull,
                           __ATOMIC_RELAXED, __HIP_MEMORY_SCOPE_AGENT);
        for (int j = 0; j < FPS_NB; ++j) {   // all 14 write -> terminates
          u64 v;
          do {
            v = __hip_atomic_load(okp + (size_t)j * SLOT_U64 + 1,
                                  __ATOMIC_RELAXED, __HIP_MEMORY_SCOPE_AGENT);
            if (v == 0ull) __builtin_amdgcn_s_sleep(1);
          } while (v == 0ull);
          if (v == 1ull) safe = 1;   // any timeout => everyone goes safe
        }
      }
    }
    s_role[0] = role; s_role[1] = safe;
  }
  __syncthreads();
  const int wid = s_role[0];
  if (wid < 0) return;               // non-elected block: done
  if (s_role[1]) fps_main<true >(pos, slots, cent_out, wid, s_w, s_bc);
  else           fps_main<false>(pos, slots, cent_out, wid, s_w, s_bc);
}

// ---------------- Ball query ----------------
#define BQ_NT  256
#define BQ_CAP 2048   // expected ~209 candidates/centroid; huge safety margin

__global__ __launch_bounds__(BQ_NT) void ballq_kernel(
    const float* __restrict__ pos,
    const float* __restrict__ cent,   // centroid coords (from d_out)
    int* __restrict__ nbr,            // [M_CENT*K_LOC]
    int* __restrict__ nsel)           // [M_CENT]
{
  __shared__ float s_d2[BQ_CAP];
  __shared__ int   s_idx[BQ_CAP];
  __shared__ int   s_count;
  __shared__ u64   s_red[BQ_NT/64];
  __shared__ u64   s_win;

  const int m = blockIdx.x, tid = threadIdx.x;
  if (tid == 0) s_count = 0;
  __syncthreads();
  const float cx = cent[3*m+0], cy = cent[3*m+1], cz = cent[3*m+2];

  for (int n = tid; n < N_PTS; n += BQ_NT) {
    float dx = __fsub_rn(cx, pos[3*n+0]);
    float dy = __fsub_rn(cy, pos[3*n+1]);
    float dz = __fsub_rn(cz, pos[3*n+2]);
    float d2 = __fadd_rn(__fadd_rn(__fmul_rn(dx,dx), __fmul_rn(dy,dy)),
                         __fmul_rn(dz,dz));
    if (d2 <= 0.01f) {   // same f32 value as (float)(0.1*0.1)
      int p = atomicAdd(&s_count, 1);
      if (p < BQ_CAP) { s_d2[p] = d2; s_idx[p] = n; }
    }
  }
  __syncthreads();
  int cnt = s_count; if (cnt > BQ_CAP) cnt = BQ_CAP;
  int ns = cnt < K_LOC ? cnt : K_LOC;

  // exact top_k semantics: k smallest d2, ties -> smaller index
  for (int sel = 0; sel < ns; sel++) {
    u64 best = ~0ull;
    for (int p = tid; p < cnt; p += BQ_NT) {
      u64 pk = ((u64)__float_as_uint(s_d2[p]) << 32) | (u64)(u32)s_idx[p];
      if (pk < best) best = pk;
    }
#pragma unroll
    for (int off = 32; off >= 1; off >>= 1) {
      u64 o = __shfl_down(best, off, 64);
      if (o < best) best = o;
    }
    if ((tid & 63) == 0) s_red[tid >> 6] = best;
    __syncthreads();
    if (tid < 64) {
      best = (tid < BQ_NT/64) ? s_red[tid] : ~0ull;
#pragma unroll
      for (int off = 2; off >= 1; off >>= 1) {
        u64 o = __shfl_down(best, off, 64);
        if (o < best) best = o;
      }
      if (tid == 0) s_win = best;
    }
    __syncthreads();
    int widx = (int)(u32)(s_win & 0xFFFFFFFFull);
    if (tid == 0) nbr[m*K_LOC + sel] = widx;
    for (int p = tid; p < cnt; p += BQ_NT) {
      if (s_idx[p] == widx) s_d2[p] = FLT_MAX;   // remove winner
    }
    __syncthreads();
  }
  if (tid == 0) nsel[m] = ns;
}

// ---------------- Gather + max-pool + channel mix ----------------
// Max over the valid selected set == reference (fallback idx is the nearest
// valid neighbor, already a member of the set).
__global__ __launch_bounds__(C_CH) void pool_mix_kernel(
    const float* __restrict__ fs,   // (N,128,1)
    const float* __restrict__ fv,   // (N,128,3)
    const float* __restrict__ Ws,
    const float* __restrict__ Wv,
    const float* __restrict__ bs,
    const float* __restrict__ bv,
    const int* __restrict__ nbr,
    const int* __restrict__ nsel,
    float* __restrict__ out_s,      // (M,128,1)
    float* __restrict__ out_v)      // (M,128,3)
{
  __shared__ float ps[C_CH];
  __shared__ float pv[C_CH*3];
  const int m = blockIdx.x, o = threadIdx.x;
  const int ns = nsel[m];
  float mS = -FLT_MAX, m0 = -FLT_MAX, m1 = -FLT_MAX, m2 = -FLT_MAX;
  for (int j = 0; j < ns; j++) {
    int n = nbr[m*K_LOC + j];
    mS = fmaxf(mS, fs[(size_t)n*C_CH + o]);
    const float* r = fv + (size_t)n*(C_CH*3) + 3*o;
    m0 = fmaxf(m0, r[0]); m1 = fmaxf(m1, r[1]); m2 = fmaxf(m2, r[2]);
  }
  ps[o] = mS; pv[3*o+0] = m0; pv[3*o+1] = m1; pv[3*o+2] = m2;
  __syncthreads();
  float aS = bs[o];
  float a0 = bv[o], a1 = bv[o], a2 = bv[o];
  for (int cc = 0; cc < C_CH; cc++) {
    float w1 = Ws[cc*C_CH + o];
    float w2 = Wv[cc*C_CH + o];
    aS = fmaf(ps[cc], w1, aS);
    a0 = fmaf(pv[3*cc+0], w2, a0);
    a1 = fmaf(pv[3*cc+1], w2, a1);
    a2 = fmaf(pv[3*cc+2], w2, a2);
  }
  out_s[(size_t)m*C_CH + o] = aS;
  float* ov = out_v + (size_t)m*(C_CH*3) + 3*o;
  ov[0] = a0; ov[1] = a1; ov[2] = a2;
}

extern "C" void kernel_launch(void* const* d_in, const int* in_sizes, int n_in,
                              void* d_out, int out_size, void* d_ws, size_t ws_size,
                              hipStream_t stream) {
  (void)in_sizes; (void)n_in; (void)out_size; (void)ws_size;
  const float* pos = (const float*)d_in[0];
  const float* fs  = (const float*)d_in[1];
  const float* fv  = (const float*)d_in[2];
  const float* Ws  = (const float*)d_in[3];
  const float* Wv  = (const float*)d_in[4];
  const float* bs  = (const float*)d_in[5];
  const float* bv  = (const float*)d_in[6];

  float* out      = (float*)d_out;
  float* cent_out = out;                               // 2048*3
  float* out_s    = out + 3*M_CENT;                    // 2048*128
  float* out_v    = out + 3*M_CENT + M_CENT*C_CH;      // 2048*128*3

  char* ws = (char*)d_ws;
  u64* slots = (u64*)ws;                               // 64*14*8*8B = 57344 B
  size_t slots_bytes = (size_t)FPS_R * FPS_NB * SLOT_U64 * 8;
  int* nbr   = (int*)(ws + slots_bytes);               // 256 KB
  int* nsel  = (int*)(ws + slots_bytes + (size_t)M_CENT*K_LOC*4);

  init_ws_kernel<<<(FPS_R*FPS_NB*SLOT_U64 + 255)/256, 256, 0, stream>>>(slots);
  fps_kernel<<<FPS_GRID, FPS_NT, 0, stream>>>(pos, slots, cent_out);
  ballq_kernel<<<M_CENT, BQ_NT, 0, stream>>>(pos, cent_out, nbr, nsel);
  pool_mix_kernel<<<M_CENT, C_CH, 0, stream>>>(fs, fv, Ws, Wv, bs, bv,
                                               nbr, nsel, out_s, out_v);
}